// Round 1
// baseline (401.223 us; speedup 1.0000x reference)
//
#include <hip/hip_runtime.h>

#define D_FT 128

// Kernel 1: row-centric SpMM + alpha residual mix.
// One wave (64 lanes) per node; lane owns 2 features (float2 -> 512B/wave coalesced).
// row[] is sorted, so the node's edge range is found by binary search
// (both bounds probed per iteration so the two dependent-load chains overlap).
__global__ __launch_bounds__(256) void spmm_mix_kernel(
    const float* __restrict__ X0,
    const int*   __restrict__ row,
    const int*   __restrict__ col,
    const float* __restrict__ vals,
    const float* __restrict__ alpha_p,
    float*       __restrict__ Xi,      // output: d_out used as Xi scratch
    int n_nodes, int n_edges)
{
    const int wave = threadIdx.x >> 6;
    const int lane = threadIdx.x & 63;
    const int node = blockIdx.x * 4 + wave;
    if (node >= n_nodes) return;

    // lower_bound(row, node) and lower_bound(row, node+1), interleaved.
    int lo0 = 0, hi0 = n_edges, lo1 = 0, hi1 = n_edges;
    while ((lo0 < hi0) || (lo1 < hi1)) {
        int m0 = (lo0 + hi0) >> 1; if (m0 >= n_edges) m0 = n_edges - 1;
        int m1 = (lo1 + hi1) >> 1; if (m1 >= n_edges) m1 = n_edges - 1;
        const int r0v = row[m0];
        const int r1v = row[m1];
        if (lo0 < hi0) { if (r0v < node)     lo0 = m0 + 1; else hi0 = m0; }
        if (lo1 < hi1) { if (r1v < node + 1) lo1 = m1 + 1; else hi1 = m1; }
    }
    const int ebeg = lo0;
    const int eend = lo1;

    const int d0 = lane * 2;
    float ax = 0.f, ay = 0.f;

    int e = ebeg;
    // 4x unrolled gather-accumulate: 4 independent loads in flight per iter.
    for (; e + 4 <= eend; e += 4) {
        const float v0 = vals[e + 0], v1 = vals[e + 1];
        const float v2 = vals[e + 2], v3 = vals[e + 3];
        const int   c0 = col[e + 0],  c1 = col[e + 1];
        const int   c2 = col[e + 2],  c3 = col[e + 3];
        const float2 x0v = *(const float2*)(X0 + (size_t)c0 * D_FT + d0);
        const float2 x1v = *(const float2*)(X0 + (size_t)c1 * D_FT + d0);
        const float2 x2v = *(const float2*)(X0 + (size_t)c2 * D_FT + d0);
        const float2 x3v = *(const float2*)(X0 + (size_t)c3 * D_FT + d0);
        ax += v0 * x0v.x + v1 * x1v.x + v2 * x2v.x + v3 * x3v.x;
        ay += v0 * x0v.y + v1 * x1v.y + v2 * x2v.y + v3 * x3v.y;
    }
    for (; e < eend; ++e) {
        const float v = vals[e];
        const int   c = col[e];
        const float2 xv = *(const float2*)(X0 + (size_t)c * D_FT + d0);
        ax += v * xv.x;
        ay += v * xv.y;
    }

    const float alpha = *alpha_p;
    const float2 x0self = *(const float2*)(X0 + (size_t)node * D_FT + d0);
    float2 xi;
    xi.x = (1.f - alpha) * ax + alpha * x0self.x;
    xi.y = (1.f - alpha) * ay + alpha * x0self.y;
    *(float2*)(Xi + (size_t)node * D_FT + d0) = xi;
}

// Kernel 2: out = (1-beta)*Xi + beta*(Xi @ W^T + b), in-place on d_out.
// 64 rows/block, 256 threads. W transposed into 64KB LDS with an XOR swizzle
// on the float4 column-granule: read (ds_read_b128) is conflict-free, staging
// writes are 8-way (one-time cost). Thread micro-tile: 8 rows x 4 cols.
// In-place safety: wave w's rows [16w,16w+16) are read only by wave w's own
// lanes, and all reads precede the stores in wave program order.
__global__ __launch_bounds__(256) void gemm_mix_kernel(
    const float* __restrict__ W,
    const float* __restrict__ bias,
    const float* __restrict__ beta_p,
    float*       __restrict__ io,     // Xi in, out in-place
    int n_nodes)
{
    __shared__ float wt[128 * 128];   // W^T, swizzled: exactly 64KB

    const int t = threadIdx.x;
    // Stage W (row-major [o][k]) transposed into wt[k][swz(o)].
    #pragma unroll
    for (int rep = 0; rep < 64; ++rep) {
        const int idx = rep * 256 + t;       // coalesced global read
        const int o = idx >> 7;
        const int k = idx & 127;
        const int g = (o >> 2) ^ (k & 7);    // swizzled float4 granule
        wt[k * 128 + (g << 2) + (o & 3)] = W[idx];
    }
    __syncthreads();

    const int tx = t & 31;        // column group: cols tx*4 .. tx*4+3
    const int ty = t >> 5;        // row group:    rows r0 .. r0+7
    const int r0 = blockIdx.x * 64 + ty * 8;
    const float beta = *beta_p;

    float4 acc[8];
    #pragma unroll
    for (int i = 0; i < 8; ++i) acc[i] = make_float4(0.f, 0.f, 0.f, 0.f);

    int rr[8];
    #pragma unroll
    for (int ry = 0; ry < 8; ++ry) {
        const int r = r0 + ry;
        rr[ry] = (r < n_nodes) ? r : (n_nodes - 1);  // clamp; results discarded
    }

    for (int k4 = 0; k4 < 128; k4 += 4) {
        float4 xi[8];
        #pragma unroll
        for (int ry = 0; ry < 8; ++ry)
            xi[ry] = *(const float4*)(io + (size_t)rr[ry] * D_FT + k4);
        #pragma unroll
        for (int kk = 0; kk < 4; ++kk) {
            const int k = k4 + kk;
            const float4 w = *(const float4*)(&wt[k * 128 + ((tx ^ (k & 7)) << 2)]);
            #pragma unroll
            for (int ry = 0; ry < 8; ++ry) {
                const float x = ((const float*)&xi[ry])[kk];
                acc[ry].x += x * w.x;
                acc[ry].y += x * w.y;
                acc[ry].z += x * w.z;
                acc[ry].w += x * w.w;
            }
        }
    }

    const float4 bb = *(const float4*)(bias + tx * 4);
    const float ob = 1.f - beta;
    #pragma unroll
    for (int ry = 0; ry < 8; ++ry) {
        const int r = r0 + ry;
        if (r < n_nodes) {
            const float4 xik = *(const float4*)(io + (size_t)r * D_FT + tx * 4);
            float4 o;
            o.x = ob * xik.x + beta * (acc[ry].x + bb.x);
            o.y = ob * xik.y + beta * (acc[ry].y + bb.y);
            o.z = ob * xik.z + beta * (acc[ry].z + bb.z);
            o.w = ob * xik.w + beta * (acc[ry].w + bb.w);
            *(float4*)(io + (size_t)r * D_FT + tx * 4) = o;
        }
    }
}

extern "C" void kernel_launch(void* const* d_in, const int* in_sizes, int n_in,
                              void* d_out, int out_size, void* d_ws, size_t ws_size,
                              hipStream_t stream) {
    // inputs: 0:X (unused) 1:X0 2:row 3:col 4:vals 5:W 6:b 7:alpha 8:beta
    const float* X0    = (const float*)d_in[1];
    const int*   row   = (const int*)  d_in[2];
    const int*   col   = (const int*)  d_in[3];
    const float* vals  = (const float*)d_in[4];
    const float* W     = (const float*)d_in[5];
    const float* b     = (const float*)d_in[6];
    const float* alpha = (const float*)d_in[7];
    const float* beta  = (const float*)d_in[8];
    float* out = (float*)d_out;

    const int n_nodes = in_sizes[1] / D_FT;
    const int n_edges = in_sizes[2];

    spmm_mix_kernel<<<(n_nodes + 3) / 4, 256, 0, stream>>>(
        X0, row, col, vals, alpha, out, n_nodes, n_edges);
    gemm_mix_kernel<<<(n_nodes + 63) / 64, 256, 0, stream>>>(
        W, b, beta, out, n_nodes);
}

// Round 3
// 274.887 us; speedup vs baseline: 1.4596x; 1.4596x over previous
//
#include <hip/hip_runtime.h>

#define D_FT 128

// ---------------------------------------------------------------------------
// bf16 helpers (round-to-nearest-even; inputs are finite)
// ---------------------------------------------------------------------------
__device__ inline unsigned f2bf(float f) {
    unsigned u = __float_as_uint(f);
    return (u + 0x7FFFu + ((u >> 16) & 1u)) >> 16;
}
__device__ inline unsigned pack2bf(float a, float b) {
    return f2bf(a) | (f2bf(b) << 16);
}

typedef __attribute__((ext_vector_type(4))) float f32x4;
typedef __attribute__((ext_vector_type(8))) short bf16x8;

// ---------------------------------------------------------------------------
// Kernel 0: build row_ptr[N+1] from sorted row[] (lower_bound table).
// ptr[i] = first edge e with row[e] >= i. Each entry written exactly once.
// ---------------------------------------------------------------------------
__global__ __launch_bounds__(256) void build_row_ptr_kernel(
    const int* __restrict__ row, int* __restrict__ ptr, int n_edges, int n_nodes)
{
    const int e = blockIdx.x * 256 + threadIdx.x;
    if (e > n_edges) return;
    const int lo = (e == 0) ? 0 : row[e - 1] + 1;
    const int hi = (e == n_edges) ? n_nodes : row[e];
    for (int i = lo; i <= hi; ++i) ptr[i] = e;
}

// ---------------------------------------------------------------------------
// Kernel 1: row-centric SpMM + alpha residual mix. One wave per node; lane
// owns 2 features (float2 -> 512B/wave coalesced gather). Edge metadata is
// loaded lane-parallel (one coalesced load per 64 edges) and broadcast via
// __shfl; gathers issued in groups of 8 for MLP.
// ---------------------------------------------------------------------------
template<bool USE_PTR>
__global__ __launch_bounds__(256) void spmm_mix_kernel(
    const float* __restrict__ X0,
    const int*   __restrict__ row,
    const int*   __restrict__ col,
    const float* __restrict__ vals,
    const int*   __restrict__ row_ptr,   // valid iff USE_PTR
    const float* __restrict__ alpha_p,
    float*       __restrict__ Xi,        // d_out used as Xi scratch
    int n_nodes, int n_edges)
{
    const int wave = threadIdx.x >> 6;
    const int lane = threadIdx.x & 63;
    const int node = blockIdx.x * 4 + wave;
    if (node >= n_nodes) return;

    int ebeg, eend;
    if (USE_PTR) {
        ebeg = row_ptr[node];
        eend = row_ptr[node + 1];
    } else {
        // fallback: interleaved double binary search
        int lo0 = 0, hi0 = n_edges, lo1 = 0, hi1 = n_edges;
        while ((lo0 < hi0) || (lo1 < hi1)) {
            int m0 = (lo0 + hi0) >> 1; if (m0 >= n_edges) m0 = n_edges - 1;
            int m1 = (lo1 + hi1) >> 1; if (m1 >= n_edges) m1 = n_edges - 1;
            const int r0v = row[m0];
            const int r1v = row[m1];
            if (lo0 < hi0) { if (r0v < node)     lo0 = m0 + 1; else hi0 = m0; }
            if (lo1 < hi1) { if (r1v < node + 1) lo1 = m1 + 1; else hi1 = m1; }
        }
        ebeg = lo0; eend = lo1;
    }

    const int d0 = lane * 2;
    float ax = 0.f, ay = 0.f;

    for (int e = ebeg; e < eend; e += 64) {
        const int n = min(64, eend - e);
        int   cl = 0; float vl = 0.f;
        if (lane < n) { cl = col[e + lane]; vl = vals[e + lane]; }
        // groups of 8 gathers in flight; j >= n lanes broadcast c=0,v=0
        for (int j0 = 0; j0 < n; j0 += 8) {
            float2 xs[8]; float vv[8];
            #pragma unroll
            for (int j = 0; j < 8; ++j) {
                const int c = __shfl(cl, j0 + j);
                vv[j] = __shfl(vl, j0 + j);
                xs[j] = *(const float2*)(X0 + (size_t)c * D_FT + d0);
            }
            #pragma unroll
            for (int j = 0; j < 8; ++j) {
                ax += vv[j] * xs[j].x;
                ay += vv[j] * xs[j].y;
            }
        }
    }

    const float alpha = *alpha_p;
    const float2 x0self = *(const float2*)(X0 + (size_t)node * D_FT + d0);
    float2 xi;
    xi.x = (1.f - alpha) * ax + alpha * x0self.x;
    xi.y = (1.f - alpha) * ay + alpha * x0self.y;
    *(float2*)(Xi + (size_t)node * D_FT + d0) = xi;
}

// ---------------------------------------------------------------------------
// Kernel 2: out = (1-beta)*Xi + beta*(Xi @ W^T + b), in-place on d_out,
// via bf16 MFMA. Block = 128 rows x 128 cols, K = 128 in one pass.
// Xi and W staged as bf16 into LDS (32KB each) with XOR swizzle
// byte ^= (row&7)<<4 so fragment ds_read_b128 are <=2-way conflicts.
// Residual term reads Xi as f32 from global (only the beta*GEMM term sees
// bf16 rounding). In-place safe: each block reads/writes only its own rows,
// and each lane's epilogue read precedes its own write.
// ---------------------------------------------------------------------------
__global__ __launch_bounds__(256) void gemm_mix_kernel(
    const float* __restrict__ W,
    const float* __restrict__ bias,
    const float* __restrict__ beta_p,
    float*       __restrict__ io,     // Xi in, out in-place
    int n_nodes)
{
    __shared__ __align__(16) char lds_raw[65536];
    char* __restrict__ ldsA = lds_raw;          // Xi tile  [128][128] bf16
    char* __restrict__ ldsB = lds_raw + 32768;  // W        [128][128] bf16

    const int t  = threadIdx.x;
    const int r0 = blockIdx.x * 128;

    // ---- stage Xi (f32 -> bf16, swizzled) ----
    #pragma unroll
    for (int i = 0; i < 16; ++i) {
        const int f4 = i * 256 + t;          // float4 index 0..4095
        const int r  = f4 >> 5;              // 0..127
        const int c4 = f4 & 31;
        int gr = r0 + r; if (gr >= n_nodes) gr = n_nodes - 1;
        const float4 x = *(const float4*)(io + (size_t)gr * D_FT + c4 * 4);
        uint2 v; v.x = pack2bf(x.x, x.y); v.y = pack2bf(x.z, x.w);
        int byte = r * 256 + c4 * 8;
        byte ^= (r & 7) << 4;
        *(uint2*)(ldsA + byte) = v;
    }
    // ---- stage W (f32 -> bf16, swizzled); layout is already B col-major ----
    #pragma unroll
    for (int i = 0; i < 16; ++i) {
        const int f4 = i * 256 + t;
        const int o  = f4 >> 5;
        const int c4 = f4 & 31;
        const float4 x = *(const float4*)(W + (size_t)o * D_FT + c4 * 4);
        uint2 v; v.x = pack2bf(x.x, x.y); v.y = pack2bf(x.z, x.w);
        int byte = o * 256 + c4 * 8;
        byte ^= (o & 7) << 4;
        *(uint2*)(ldsB + byte) = v;
    }
    __syncthreads();

    const int w   = t >> 6;
    const int l   = t & 63;
    const int lhi = l >> 4;     // 0..3
    const int llo = l & 15;

    f32x4 acc[2][8];
    #pragma unroll
    for (int m = 0; m < 2; ++m)
        #pragma unroll
        for (int n = 0; n < 8; ++n)
            acc[m][n] = (f32x4){0.f, 0.f, 0.f, 0.f};

    #pragma unroll
    for (int ks = 0; ks < 4; ++ks) {
        const int kb = ks * 64 + lhi * 16;   // byte offset of this lane's k-slice
        bf16x8 a[2], b[8];
        #pragma unroll
        for (int m = 0; m < 2; ++m) {
            const int r = w * 32 + m * 16 + llo;
            int byte = r * 256 + kb;
            byte ^= (r & 7) << 4;
            a[m] = *(const bf16x8*)(ldsA + byte);
        }
        #pragma unroll
        for (int n = 0; n < 8; ++n) {
            const int o = n * 16 + llo;
            int byte = o * 256 + kb;
            byte ^= (o & 7) << 4;
            b[n] = *(const bf16x8*)(ldsB + byte);
        }
        #pragma unroll
        for (int m = 0; m < 2; ++m)
            #pragma unroll
            for (int n = 0; n < 8; ++n)
                acc[m][n] = __builtin_amdgcn_mfma_f32_16x16x32_bf16(
                    a[m], b[n], acc[m][n], 0, 0, 0);
    }

    // ---- epilogue: out = (1-beta)*Xi_f32 + beta*(acc + bias) ----
    const float beta = *beta_p;
    const float ob = 1.f - beta;
    float bb[8];
    #pragma unroll
    for (int n = 0; n < 8; ++n) bb[n] = bias[n * 16 + llo];

    #pragma unroll
    for (int m = 0; m < 2; ++m) {
        const int rbase = r0 + w * 32 + m * 16 + lhi * 4;
        #pragma unroll
        for (int q = 0; q < 4; ++q) {
            const int R = rbase + q;
            if (R < n_nodes) {
                #pragma unroll
                for (int n = 0; n < 8; ++n) {
                    const int C = n * 16 + llo;
                    const float xi = io[(size_t)R * D_FT + C];
                    io[(size_t)R * D_FT + C] = ob * xi + beta * (acc[m][n][q] + bb[n]);
                }
            }
        }
    }
}

extern "C" void kernel_launch(void* const* d_in, const int* in_sizes, int n_in,
                              void* d_out, int out_size, void* d_ws, size_t ws_size,
                              hipStream_t stream) {
    // inputs: 0:X (unused) 1:X0 2:row 3:col 4:vals 5:W 6:b 7:alpha 8:beta
    const float* X0    = (const float*)d_in[1];
    const int*   row   = (const int*)  d_in[2];
    const int*   col   = (const int*)  d_in[3];
    const float* vals  = (const float*)d_in[4];
    const float* W     = (const float*)d_in[5];
    const float* b     = (const float*)d_in[6];
    const float* alpha = (const float*)d_in[7];
    const float* beta  = (const float*)d_in[8];
    float* out = (float*)d_out;

    const int n_nodes = in_sizes[1] / D_FT;
    const int n_edges = in_sizes[2];

    const size_t ptr_bytes = (size_t)(n_nodes + 1) * sizeof(int);
    const bool use_ptr = (ws_size >= ptr_bytes);

    if (use_ptr) {
        int* row_ptr = (int*)d_ws;
        build_row_ptr_kernel<<<(n_edges + 256) / 256, 256, 0, stream>>>(
            row, row_ptr, n_edges, n_nodes);
        spmm_mix_kernel<true><<<(n_nodes + 3) / 4, 256, 0, stream>>>(
            X0, row, col, vals, row_ptr, alpha, out, n_nodes, n_edges);
    } else {
        spmm_mix_kernel<false><<<(n_nodes + 3) / 4, 256, 0, stream>>>(
            X0, row, col, vals, nullptr, alpha, out, n_nodes, n_edges);
    }
    gemm_mix_kernel<<<(n_nodes + 127) / 128, 256, 0, stream>>>(
        W, b, beta, out, n_nodes);
}

// Round 6
// 274.859 us; speedup vs baseline: 1.4597x; 1.0001x over previous
//
#include <hip/hip_runtime.h>

#define D_FT 128

// ---------------------------------------------------------------------------
// bf16 helpers (round-to-nearest-even; inputs are finite)
// ---------------------------------------------------------------------------
__device__ inline unsigned f2bf(float f) {
    unsigned u = __float_as_uint(f);
    return (u + 0x7FFFu + ((u >> 16) & 1u)) >> 16;
}
__device__ inline unsigned pack2bf(float a, float b) {
    return f2bf(a) | (f2bf(b) << 16);
}

typedef __attribute__((ext_vector_type(4))) float f32x4;
typedef __attribute__((ext_vector_type(8))) short bf16x8;

union bf8u { bf16x8 v; unsigned u[4]; };

// ---------------------------------------------------------------------------
// Kernel 0: build row_ptr[N+1] from sorted row[] (lower_bound table).
// ---------------------------------------------------------------------------
__global__ __launch_bounds__(256) void build_row_ptr_kernel(
    const int* __restrict__ row, int* __restrict__ ptr, int n_edges, int n_nodes)
{
    const int e = blockIdx.x * 256 + threadIdx.x;
    if (e > n_edges) return;
    const int lo = (e == 0) ? 0 : row[e - 1] + 1;
    const int hi = (e == n_edges) ? n_nodes : row[e];
    for (int i = lo; i <= hi; ++i) ptr[i] = e;
}

// ---------------------------------------------------------------------------
// Kernel 1: row-centric SpMM + alpha residual mix. One wave per node; lane
// owns 2 features (float2 -> 512B/wave coalesced gather). Edge metadata
// loaded lane-parallel, broadcast via __shfl; gathers 16-deep for MLP.
// Inactive tail lanes carry (c=0, v=0): harmless hot-line gather, zero
// contribution -> no predication in the inner loop.
// ---------------------------------------------------------------------------
template<bool USE_PTR>
__global__ __launch_bounds__(256) void spmm_mix_kernel(
    const float* __restrict__ X0,
    const int*   __restrict__ row,
    const int*   __restrict__ col,
    const float* __restrict__ vals,
    const int*   __restrict__ row_ptr,   // valid iff USE_PTR
    const float* __restrict__ alpha_p,
    float*       __restrict__ Xi,        // d_out used as Xi scratch
    int n_nodes, int n_edges)
{
    const int wave = threadIdx.x >> 6;
    const int lane = threadIdx.x & 63;
    const int node = blockIdx.x * 4 + wave;
    if (node >= n_nodes) return;

    int ebeg, eend;
    if (USE_PTR) {
        ebeg = row_ptr[node];
        eend = row_ptr[node + 1];
    } else {
        int lo0 = 0, hi0 = n_edges, lo1 = 0, hi1 = n_edges;
        while ((lo0 < hi0) || (lo1 < hi1)) {
            int m0 = (lo0 + hi0) >> 1; if (m0 >= n_edges) m0 = n_edges - 1;
            int m1 = (lo1 + hi1) >> 1; if (m1 >= n_edges) m1 = n_edges - 1;
            const int r0v = row[m0];
            const int r1v = row[m1];
            if (lo0 < hi0) { if (r0v < node)     lo0 = m0 + 1; else hi0 = m0; }
            if (lo1 < hi1) { if (r1v < node + 1) lo1 = m1 + 1; else hi1 = m1; }
        }
        ebeg = lo0; eend = lo1;
    }

    const int d0 = lane * 2;
    float ax = 0.f, ay = 0.f;

    for (int e = ebeg; e < eend; e += 64) {
        const int n = min(64, eend - e);
        int   cl = 0; float vl = 0.f;
        if (lane < n) { cl = col[e + lane]; vl = vals[e + lane]; }
        for (int j0 = 0; j0 < n; j0 += 16) {
            float2 xs[16]; float vv[16];
            #pragma unroll
            for (int j = 0; j < 16; ++j) {
                const int c = __shfl(cl, j0 + j);   // lanes >= n give c=0
                vv[j] = __shfl(vl, j0 + j);         // ... and v=0
                xs[j] = *(const float2*)(X0 + (size_t)c * D_FT + d0);
            }
            #pragma unroll
            for (int j = 0; j < 16; ++j) {
                ax += vv[j] * xs[j].x;
                ay += vv[j] * xs[j].y;
            }
        }
    }

    const float alpha = *alpha_p;
    const float2 x0self = *(const float2*)(X0 + (size_t)node * D_FT + d0);
    float2 xi;
    xi.x = (1.f - alpha) * ax + alpha * x0self.x;
    xi.y = (1.f - alpha) * ay + alpha * x0self.y;
    *(float2*)(Xi + (size_t)node * D_FT + d0) = xi;
}

// ---------------------------------------------------------------------------
// Kernel 2 v2: out = (1-beta)*Xi + beta*(Xi @ W^T + b), in-place on d_out.
// Tile M=64 per block (4 waves x 16 rows), K=128 one pass, bf16 MFMA.
// LDS = 32 KB only: W (bf16, XOR-swizzled) during MFMA phase, then the SAME
// buffer is reused as f32 [64][128] output-transpose scratch -> 5 blocks/CU.
// A-fragments load straight from global (issued before W staging for
// latency overlap). Epilogue is fully float4-vectorized.
// In-place safe: block touches only its own 64 rows; all fragment reads
// complete before the barrier preceding the stores.
// ---------------------------------------------------------------------------
__global__ __launch_bounds__(256) void gemm_mix_kernel(
    const float* __restrict__ W,
    const float* __restrict__ bias,
    const float* __restrict__ beta_p,
    float*       __restrict__ io,     // Xi in, out in-place
    int n_nodes)
{
    __shared__ __align__(16) char lds_raw[32768];
    char*  __restrict__ ldsB = lds_raw;             // W [128][128] bf16, swizzled
    float* __restrict__ ldsS = (float*)lds_raw;     // later: out [64][128] f32

    const int t   = threadIdx.x;
    const int w   = t >> 6;
    const int l   = t & 63;
    const int lhi = l >> 4;     // 0..3
    const int llo = l & 15;
    const int r0  = blockIdx.x * 64;

    // ---- issue A-fragment loads first (global f32, 2 x float4 per ks) ----
    int arow = r0 + w * 16 + llo;
    if (arow >= n_nodes) arow = n_nodes - 1;        // clamped rows discarded later
    const float* aptr = io + (size_t)arow * D_FT;
    float4 af0[4], af1[4];
    #pragma unroll
    for (int ks = 0; ks < 4; ++ks) {
        const int k0 = ks * 32 + lhi * 8;
        af0[ks] = *(const float4*)(aptr + k0);
        af1[ks] = *(const float4*)(aptr + k0 + 4);
    }

    // ---- stage W (f32 -> bf16, swizzled) ----
    #pragma unroll
    for (int i = 0; i < 16; ++i) {
        const int f4 = i * 256 + t;
        const int o  = f4 >> 5;
        const int c4 = f4 & 31;
        const float4 x = *(const float4*)(W + (size_t)o * D_FT + c4 * 4);
        uint2 v; v.x = pack2bf(x.x, x.y); v.y = pack2bf(x.z, x.w);
        int byte = o * 256 + c4 * 8;
        byte ^= (o & 7) << 4;
        *(uint2*)(ldsB + byte) = v;
    }
    __syncthreads();

    // ---- MFMA: 4 k-slices x 8 col-fragments ----
    f32x4 acc[8];
    #pragma unroll
    for (int n = 0; n < 8; ++n) acc[n] = (f32x4){0.f, 0.f, 0.f, 0.f};

    #pragma unroll
    for (int ks = 0; ks < 4; ++ks) {
        bf8u a;
        a.u[0] = pack2bf(af0[ks].x, af0[ks].y);
        a.u[1] = pack2bf(af0[ks].z, af0[ks].w);
        a.u[2] = pack2bf(af1[ks].x, af1[ks].y);
        a.u[3] = pack2bf(af1[ks].z, af1[ks].w);
        const int kb = ks * 64 + lhi * 16;
        #pragma unroll
        for (int n = 0; n < 8; ++n) {
            const int o = n * 16 + llo;
            int byte = o * 256 + kb;
            byte ^= (o & 7) << 4;
            const bf16x8 b = *(const bf16x8*)(ldsB + byte);
            acc[n] = __builtin_amdgcn_mfma_f32_16x16x32_bf16(a.v, b, acc[n], 0, 0, 0);
        }
    }

    // ---- transpose acc through LDS (W no longer needed) ----
    __syncthreads();            // everyone done reading W
    #pragma unroll
    for (int n = 0; n < 8; ++n) {
        const int C = n * 16 + llo;
        const int rt = w * 16 + lhi * 4;
        #pragma unroll
        for (int q = 0; q < 4; ++q)
            ldsS[(rt + q) * 128 + C] = acc[n][q];
    }
    __syncthreads();

    // ---- vectorized epilogue: out = (1-beta)*Xi + beta*(acc + bias) ----
    const float beta = *beta_p;
    const float ob = 1.f - beta;
    const int c4 = t & 31;            // float4 column chunk
    const int rb = t >> 5;            // 0..7
    const float4 bb = *(const float4*)(bias + c4 * 4);

    #pragma unroll
    for (int i = 0; i < 8; ++i) {
        const int r  = rb * 8 + i;
        const int gr = r0 + r;
        if (gr < n_nodes) {
            const float4 a4  = *(const float4*)(ldsS + r * 128 + c4 * 4);
            const float4 xi4 = *(const float4*)(io + (size_t)gr * D_FT + c4 * 4);
            float4 o;
            o.x = ob * xi4.x + beta * (a4.x + bb.x);
            o.y = ob * xi4.y + beta * (a4.y + bb.y);
            o.z = ob * xi4.z + beta * (a4.z + bb.z);
            o.w = ob * xi4.w + beta * (a4.w + bb.w);
            *(float4*)(io + (size_t)gr * D_FT + c4 * 4) = o;
        }
    }
}

extern "C" void kernel_launch(void* const* d_in, const int* in_sizes, int n_in,
                              void* d_out, int out_size, void* d_ws, size_t ws_size,
                              hipStream_t stream) {
    // inputs: 0:X (unused) 1:X0 2:row 3:col 4:vals 5:W 6:b 7:alpha 8:beta
    const float* X0    = (const float*)d_in[1];
    const int*   row   = (const int*)  d_in[2];
    const int*   col   = (const int*)  d_in[3];
    const float* vals  = (const float*)d_in[4];
    const float* W     = (const float*)d_in[5];
    const float* b     = (const float*)d_in[6];
    const float* alpha = (const float*)d_in[7];
    const float* beta  = (const float*)d_in[8];
    float* out = (float*)d_out;

    const int n_nodes = in_sizes[1] / D_FT;
    const int n_edges = in_sizes[2];

    const size_t ptr_bytes = (size_t)(n_nodes + 1) * sizeof(int);
    const bool use_ptr = (ws_size >= ptr_bytes);

    if (use_ptr) {
        int* row_ptr = (int*)d_ws;
        build_row_ptr_kernel<<<(n_edges + 256) / 256, 256, 0, stream>>>(
            row, row_ptr, n_edges, n_nodes);
        spmm_mix_kernel<true><<<(n_nodes + 3) / 4, 256, 0, stream>>>(
            X0, row, col, vals, row_ptr, alpha, out, n_nodes, n_edges);
    } else {
        spmm_mix_kernel<false><<<(n_nodes + 3) / 4, 256, 0, stream>>>(
            X0, row, col, vals, nullptr, alpha, out, n_nodes, n_edges);
    }
    gemm_mix_kernel<<<(n_nodes + 63) / 64, 256, 0, stream>>>(
        W, b, beta, out, n_nodes);
}

// Round 7
// 242.778 us; speedup vs baseline: 1.6526x; 1.1321x over previous
//
#include <hip/hip_runtime.h>

#define D_FT 128

// ---------------------------------------------------------------------------
// bf16 helpers (round-to-nearest-even; inputs are finite)
// ---------------------------------------------------------------------------
__device__ inline unsigned f2bf(float f) {
    unsigned u = __float_as_uint(f);
    return (u + 0x7FFFu + ((u >> 16) & 1u)) >> 16;
}
__device__ inline unsigned pack2bf(float a, float b) {
    return f2bf(a) | (f2bf(b) << 16);
}
__device__ inline float bf_lo(unsigned u) { return __uint_as_float(u << 16); }
__device__ inline float bf_hi(unsigned u) { return __uint_as_float(u & 0xFFFF0000u); }

typedef __attribute__((ext_vector_type(4))) float f32x4;
typedef __attribute__((ext_vector_type(8))) short bf16x8;

// ---------------------------------------------------------------------------
// Kernel A: convert X0 (f32) -> bf16 packed (2 per word), streaming.
// ---------------------------------------------------------------------------
__global__ __launch_bounds__(256) void convert_x0_kernel(
    const float* __restrict__ X0, unsigned* __restrict__ xb, int n4)
{
    const int i = blockIdx.x * 256 + threadIdx.x;   // one float4 -> one uint2
    if (i < n4) {
        const float4 x = ((const float4*)X0)[i];
        uint2 v; v.x = pack2bf(x.x, x.y); v.y = pack2bf(x.z, x.w);
        ((uint2*)xb)[i] = v;
    }
}

// ---------------------------------------------------------------------------
// Kernel 0: build row_ptr[N+1] from sorted row[] (lower_bound table).
// ---------------------------------------------------------------------------
__global__ __launch_bounds__(256) void build_row_ptr_kernel(
    const int* __restrict__ row, int* __restrict__ ptr, int n_edges, int n_nodes)
{
    const int e = blockIdx.x * 256 + threadIdx.x;
    if (e > n_edges) return;
    const int lo = (e == 0) ? 0 : row[e - 1] + 1;
    const int hi = (e == n_edges) ? n_nodes : row[e];
    for (int i = lo; i <= hi; ++i) ptr[i] = e;
}

// ---------------------------------------------------------------------------
// Kernel 1: row-centric SpMM + alpha residual mix. One wave per node; lane
// owns 2 features. GB: gather from bf16 X0 copy (256B/row, halves the
// behind-L2 gather bytes = the measured 3.76 TB/s wall). XB: store Xi as
// bf16 into ws (halves Xi write traffic; feeds MFMA directly).
// Self X0 term always read f32 (accuracy).
// ---------------------------------------------------------------------------
template<bool GB, bool XB, bool PTR>
__global__ __launch_bounds__(256) void spmm_mix_kernel(
    const float*    __restrict__ X0,
    const unsigned* __restrict__ X0b,      // valid iff GB
    const int*      __restrict__ row,
    const int*      __restrict__ col,
    const float*    __restrict__ vals,
    const int*      __restrict__ row_ptr,  // valid iff PTR
    const float*    __restrict__ alpha_p,
    float*          __restrict__ Xi_f32,   // valid iff !XB (d_out)
    unsigned*       __restrict__ Xi_bf,    // valid iff XB  (ws)
    int n_nodes, int n_edges)
{
    const int wave = threadIdx.x >> 6;
    const int lane = threadIdx.x & 63;
    const int node = blockIdx.x * 4 + wave;
    if (node >= n_nodes) return;

    int ebeg, eend;
    if (PTR) {
        ebeg = row_ptr[node];
        eend = row_ptr[node + 1];
    } else {
        int lo0 = 0, hi0 = n_edges, lo1 = 0, hi1 = n_edges;
        while ((lo0 < hi0) || (lo1 < hi1)) {
            int m0 = (lo0 + hi0) >> 1; if (m0 >= n_edges) m0 = n_edges - 1;
            int m1 = (lo1 + hi1) >> 1; if (m1 >= n_edges) m1 = n_edges - 1;
            const int r0v = row[m0];
            const int r1v = row[m1];
            if (lo0 < hi0) { if (r0v < node)     lo0 = m0 + 1; else hi0 = m0; }
            if (lo1 < hi1) { if (r1v < node + 1) lo1 = m1 + 1; else hi1 = m1; }
        }
        ebeg = lo0; eend = lo1;
    }

    const int d0 = lane * 2;
    float ax = 0.f, ay = 0.f;

    for (int e = ebeg; e < eend; e += 64) {
        const int n = min(64, eend - e);
        int   cl = 0; float vl = 0.f;
        if (lane < n) { cl = col[e + lane]; vl = vals[e + lane]; }
        for (int j0 = 0; j0 < n; j0 += 16) {
            float vv[16];
            if (GB) {
                unsigned xs[16];
                #pragma unroll
                for (int j = 0; j < 16; ++j) {
                    const int c = __shfl(cl, j0 + j);   // lanes >= n give c=0
                    vv[j] = __shfl(vl, j0 + j);         // ... and v=0
                    xs[j] = X0b[c * 64 + lane];         // 2 bf16 = 4B/lane
                }
                #pragma unroll
                for (int j = 0; j < 16; ++j) {
                    ax += vv[j] * bf_lo(xs[j]);
                    ay += vv[j] * bf_hi(xs[j]);
                }
            } else {
                float2 xs[16];
                #pragma unroll
                for (int j = 0; j < 16; ++j) {
                    const int c = __shfl(cl, j0 + j);
                    vv[j] = __shfl(vl, j0 + j);
                    xs[j] = *(const float2*)(X0 + (size_t)c * D_FT + d0);
                }
                #pragma unroll
                for (int j = 0; j < 16; ++j) {
                    ax += vv[j] * xs[j].x;
                    ay += vv[j] * xs[j].y;
                }
            }
        }
    }

    const float alpha = *alpha_p;
    const float2 x0self = *(const float2*)(X0 + (size_t)node * D_FT + d0);
    float2 xi;
    xi.x = (1.f - alpha) * ax + alpha * x0self.x;
    xi.y = (1.f - alpha) * ay + alpha * x0self.y;
    if (XB) {
        Xi_bf[node * 64 + lane] = pack2bf(xi.x, xi.y);
    } else {
        *(float2*)(Xi_f32 + (size_t)node * D_FT + d0) = xi;
    }
}

// ---------------------------------------------------------------------------
// Kernel 2a (bf16-ws path): out = (1-beta)*Xi + beta*(Xi @ W^T + b).
// Xi is bf16-packed in ws; A-fragments are direct 16B loads (no conversion).
// out is PURE WRITE. W staged bf16 XOR-swizzled in 32KB LDS, then the LDS is
// reused as f32 [64][128] transpose scratch for a float4 epilogue.
// ---------------------------------------------------------------------------
__global__ __launch_bounds__(256) void gemm_mix_bf16_kernel(
    const float*    __restrict__ W,
    const float*    __restrict__ bias,
    const float*    __restrict__ beta_p,
    const unsigned* __restrict__ xi,      // bf16 packed, 64 words/row
    float*          __restrict__ out,
    int n_nodes)
{
    __shared__ __align__(16) char lds_raw[32768];
    char*  __restrict__ ldsB = lds_raw;             // W [128][128] bf16, swizzled
    float* __restrict__ ldsS = (float*)lds_raw;     // later: out [64][128] f32

    const int t   = threadIdx.x;
    const int w   = t >> 6;
    const int l   = t & 63;
    const int lhi = l >> 4;
    const int llo = l & 15;
    const int r0  = blockIdx.x * 64;

    // ---- A-fragments: direct bf16 loads from ws (issued first) ----
    int arow = r0 + w * 16 + llo;
    if (arow >= n_nodes) arow = n_nodes - 1;
    const char* aptr = (const char*)xi + (size_t)arow * 256;
    bf16x8 a[4];
    #pragma unroll
    for (int ks = 0; ks < 4; ++ks)
        a[ks] = *(const bf16x8*)(aptr + ks * 64 + lhi * 16);

    // ---- stage W (f32 -> bf16, swizzled) ----
    #pragma unroll
    for (int i = 0; i < 16; ++i) {
        const int f4 = i * 256 + t;
        const int o  = f4 >> 5;
        const int c4 = f4 & 31;
        const float4 x = *(const float4*)(W + (size_t)o * D_FT + c4 * 4);
        uint2 v; v.x = pack2bf(x.x, x.y); v.y = pack2bf(x.z, x.w);
        int byte = o * 256 + c4 * 8;
        byte ^= (o & 7) << 4;
        *(uint2*)(ldsB + byte) = v;
    }
    __syncthreads();

    // ---- MFMA: 4 k-slices x 8 col-fragments ----
    f32x4 acc[8];
    #pragma unroll
    for (int n = 0; n < 8; ++n) acc[n] = (f32x4){0.f, 0.f, 0.f, 0.f};

    #pragma unroll
    for (int ks = 0; ks < 4; ++ks) {
        const int kb = ks * 64 + lhi * 16;
        #pragma unroll
        for (int n = 0; n < 8; ++n) {
            const int o = n * 16 + llo;
            int byte = o * 256 + kb;
            byte ^= (o & 7) << 4;
            const bf16x8 b = *(const bf16x8*)(ldsB + byte);
            acc[n] = __builtin_amdgcn_mfma_f32_16x16x32_bf16(a[ks], b, acc[n], 0, 0, 0);
        }
    }

    // ---- transpose acc through LDS (W no longer needed) ----
    __syncthreads();
    #pragma unroll
    for (int n = 0; n < 8; ++n) {
        const int C = n * 16 + llo;
        const int rt = w * 16 + lhi * 4;
        #pragma unroll
        for (int q = 0; q < 4; ++q)
            ldsS[(rt + q) * 128 + C] = acc[n][q];
    }
    __syncthreads();

    // ---- float4 epilogue: residual from bf16 Xi, pure write to out ----
    const float beta = *beta_p;
    const float ob = 1.f - beta;
    const int c4 = t & 31;
    const int rb = t >> 5;
    const float4 bb = *(const float4*)(bias + c4 * 4);

    #pragma unroll
    for (int i = 0; i < 8; ++i) {
        const int r  = rb * 8 + i;
        const int gr = r0 + r;
        if (gr < n_nodes) {
            const float4 a4 = *(const float4*)(ldsS + r * 128 + c4 * 4);
            const uint2  p  = ((const uint2*)(xi + (size_t)gr * 64))[c4];
            float4 o;
            o.x = ob * bf_lo(p.x) + beta * (a4.x + bb.x);
            o.y = ob * bf_hi(p.x) + beta * (a4.y + bb.y);
            o.z = ob * bf_lo(p.y) + beta * (a4.z + bb.z);
            o.w = ob * bf_hi(p.y) + beta * (a4.w + bb.w);
            *(float4*)(out + (size_t)gr * D_FT + c4 * 4) = o;
        }
    }
}

// ---------------------------------------------------------------------------
// Kernel 2b (f32 fallback, R6-validated): in-place on d_out.
// ---------------------------------------------------------------------------
union bf8u { bf16x8 v; unsigned u[4]; };

__global__ __launch_bounds__(256) void gemm_mix_f32_kernel(
    const float* __restrict__ W,
    const float* __restrict__ bias,
    const float* __restrict__ beta_p,
    float*       __restrict__ io,
    int n_nodes)
{
    __shared__ __align__(16) char lds_raw[32768];
    char*  __restrict__ ldsB = lds_raw;
    float* __restrict__ ldsS = (float*)lds_raw;

    const int t   = threadIdx.x;
    const int w   = t >> 6;
    const int l   = t & 63;
    const int lhi = l >> 4;
    const int llo = l & 15;
    const int r0  = blockIdx.x * 64;

    int arow = r0 + w * 16 + llo;
    if (arow >= n_nodes) arow = n_nodes - 1;
    const float* aptr = io + (size_t)arow * D_FT;
    float4 af0[4], af1[4];
    #pragma unroll
    for (int ks = 0; ks < 4; ++ks) {
        const int k0 = ks * 32 + lhi * 8;
        af0[ks] = *(const float4*)(aptr + k0);
        af1[ks] = *(const float4*)(aptr + k0 + 4);
    }

    #pragma unroll
    for (int i = 0; i < 16; ++i) {
        const int f4 = i * 256 + t;
        const int o  = f4 >> 5;
        const int c4 = f4 & 31;
        const float4 x = *(const float4*)(W + (size_t)o * D_FT + c4 * 4);
        uint2 v; v.x = pack2bf(x.x, x.y); v.y = pack2bf(x.z, x.w);
        int byte = o * 256 + c4 * 8;
        byte ^= (o & 7) << 4;
        *(uint2*)(ldsB + byte) = v;
    }
    __syncthreads();

    f32x4 acc[8];
    #pragma unroll
    for (int n = 0; n < 8; ++n) acc[n] = (f32x4){0.f, 0.f, 0.f, 0.f};

    #pragma unroll
    for (int ks = 0; ks < 4; ++ks) {
        bf8u a;
        a.u[0] = pack2bf(af0[ks].x, af0[ks].y);
        a.u[1] = pack2bf(af0[ks].z, af0[ks].w);
        a.u[2] = pack2bf(af1[ks].x, af1[ks].y);
        a.u[3] = pack2bf(af1[ks].z, af1[ks].w);
        const int kb = ks * 64 + lhi * 16;
        #pragma unroll
        for (int n = 0; n < 8; ++n) {
            const int o = n * 16 + llo;
            int byte = o * 256 + kb;
            byte ^= (o & 7) << 4;
            const bf16x8 b = *(const bf16x8*)(ldsB + byte);
            acc[n] = __builtin_amdgcn_mfma_f32_16x16x32_bf16(a.v, b, acc[n], 0, 0, 0);
        }
    }

    __syncthreads();
    #pragma unroll
    for (int n = 0; n < 8; ++n) {
        const int C = n * 16 + llo;
        const int rt = w * 16 + lhi * 4;
        #pragma unroll
        for (int q = 0; q < 4; ++q)
            ldsS[(rt + q) * 128 + C] = acc[n][q];
    }
    __syncthreads();

    const float beta = *beta_p;
    const float ob = 1.f - beta;
    const int c4 = t & 31;
    const int rb = t >> 5;
    const float4 bb = *(const float4*)(bias + c4 * 4);

    #pragma unroll
    for (int i = 0; i < 8; ++i) {
        const int r  = rb * 8 + i;
        const int gr = r0 + r;
        if (gr < n_nodes) {
            const float4 a4  = *(const float4*)(ldsS + r * 128 + c4 * 4);
            const float4 xi4 = *(const float4*)(io + (size_t)gr * D_FT + c4 * 4);
            float4 o;
            o.x = ob * xi4.x + beta * (a4.x + bb.x);
            o.y = ob * xi4.y + beta * (a4.y + bb.y);
            o.z = ob * xi4.z + beta * (a4.z + bb.z);
            o.w = ob * xi4.w + beta * (a4.w + bb.w);
            *(float4*)(io + (size_t)gr * D_FT + c4 * 4) = o;
        }
    }
}

extern "C" void kernel_launch(void* const* d_in, const int* in_sizes, int n_in,
                              void* d_out, int out_size, void* d_ws, size_t ws_size,
                              hipStream_t stream) {
    // inputs: 0:X (unused) 1:X0 2:row 3:col 4:vals 5:W 6:b 7:alpha 8:beta
    const float* X0    = (const float*)d_in[1];
    const int*   row   = (const int*)  d_in[2];
    const int*   col   = (const int*)  d_in[3];
    const float* vals  = (const float*)d_in[4];
    const float* W     = (const float*)d_in[5];
    const float* b     = (const float*)d_in[6];
    const float* alpha = (const float*)d_in[7];
    const float* beta  = (const float*)d_in[8];
    float* out = (float*)d_out;

    const int n_nodes = in_sizes[1] / D_FT;
    const int n_edges = in_sizes[2];

    const size_t ptr_bytes = (size_t)(n_nodes + 1) * sizeof(int);
    const size_t BFOFF  = 524288;                       // 512 KB, past row_ptr
    const size_t BFSZ   = (size_t)n_nodes * 256;        // one bf16 [N][128]
    const bool ptr_ok = (ws_size >= ptr_bytes);
    const bool tierA  = ptr_ok && (ws_size >= BFOFF + 2 * BFSZ);  // X0b + Xi
    const bool tierAp = !tierA && ptr_ok && (ws_size >= BFOFF + BFSZ); // Xi only

    int* row_ptr = (int*)d_ws;
    if (ptr_ok)
        build_row_ptr_kernel<<<(n_edges + 256) / 256, 256, 0, stream>>>(
            row, row_ptr, n_edges, n_nodes);

    const int spmm_grid = (n_nodes + 3) / 4;

    if (tierA) {
        unsigned* X0b  = (unsigned*)((char*)d_ws + BFOFF);
        unsigned* Xibf = (unsigned*)((char*)d_ws + BFOFF + BFSZ);
        const int n4 = n_nodes * D_FT / 4;
        convert_x0_kernel<<<(n4 + 255) / 256, 256, 0, stream>>>(X0, X0b, n4);
        spmm_mix_kernel<true, true, true><<<spmm_grid, 256, 0, stream>>>(
            X0, X0b, row, col, vals, row_ptr, alpha, nullptr, Xibf,
            n_nodes, n_edges);
        gemm_mix_bf16_kernel<<<(n_nodes + 63) / 64, 256, 0, stream>>>(
            W, b, beta, Xibf, out, n_nodes);
    } else if (tierAp) {
        unsigned* Xibf = (unsigned*)((char*)d_ws + BFOFF);
        spmm_mix_kernel<false, true, true><<<spmm_grid, 256, 0, stream>>>(
            X0, nullptr, row, col, vals, row_ptr, alpha, nullptr, Xibf,
            n_nodes, n_edges);
        gemm_mix_bf16_kernel<<<(n_nodes + 63) / 64, 256, 0, stream>>>(
            W, b, beta, Xibf, out, n_nodes);
    } else if (ptr_ok) {
        spmm_mix_kernel<false, false, true><<<spmm_grid, 256, 0, stream>>>(
            X0, nullptr, row, col, vals, row_ptr, alpha, out, nullptr,
            n_nodes, n_edges);
        gemm_mix_f32_kernel<<<(n_nodes + 63) / 64, 256, 0, stream>>>(
            W, b, beta, out, n_nodes);
    } else {
        spmm_mix_kernel<false, false, false><<<spmm_grid, 256, 0, stream>>>(
            X0, nullptr, row, col, vals, nullptr, alpha, out, nullptr,
            n_nodes, n_edges);
        gemm_mix_f32_kernel<<<(n_nodes + 63) / 64, 256, 0, stream>>>(
            W, b, beta, out, n_nodes);
    }
}